// Round 7
// baseline (307.656 us; speedup 1.0000x reference)
//
#include <hip/hip_runtime.h>
#include <stdint.h>

// Problem: B=8, Lq=Lv=2048, Din=Dout=512, all f32 in/out.
// out[b][l][0:512)=o, [512:1024)=q, [1024:1536)=mv broadcast.
// Structure: r3-verified flash (dual-layout LDS tiles, XOR-swizzled A-tile)
// + counted-vmcnt double-barrier pipeline + LDS-resident mask + fused epilogue.

typedef __attribute__((ext_vector_type(8))) short short8v;
typedef __attribute__((ext_vector_type(4))) float f32x4;

#define LQ 2048
#define LV 2048
#define DIN 512
#define DOUT 512
#define NB 8
#define KT 32   // KV tile

__device__ __forceinline__ unsigned short f2bf(float x){
    union { float f; unsigned u; } v; v.f = x;
    unsigned r = v.u + 0x7fffu + ((v.u >> 16) & 1u);
    return (unsigned short)(r >> 16);
}

// async global->LDS, 16B per lane; LDS dest = wave-uniform base + lane*16
__device__ __forceinline__ void gload16(const void* g, void* l){
    __builtin_amdgcn_global_load_lds((const __attribute__((address_space(1))) void*)g,
                                     (__attribute__((address_space(3))) void*)l, 16, 0, 0);
}

#define SBAR    do{ __builtin_amdgcn_s_barrier(); __builtin_amdgcn_sched_barrier(0); }while(0)
#define VMCNT16 do{ asm volatile("s_waitcnt vmcnt(16)" ::: "memory"); \
                    __builtin_amdgcn_sched_barrier(0); }while(0)
#define VMCNT0  do{ asm volatile("s_waitcnt vmcnt(0)" ::: "memory"); \
                    __builtin_amdgcn_sched_barrier(0); }while(0)

// kernel [DIN][DOUT] f32 -> kT [DOUT][DIN] bf16, scaled by 0.1 (folds the /10)
__global__ void prep_kT(const float* __restrict__ k, unsigned short* __restrict__ kT){
    __shared__ float tile[32][33];
    int tx = threadIdx.x & 31, ty = threadIdx.x >> 5;
    int kb = blockIdx.x, eb = blockIdx.y;
    #pragma unroll
    for (int p = 0; p < 4; ++p){
        int r = ty + p*8;
        tile[r][tx] = k[(size_t)(kb*32 + r)*DOUT + eb*32 + tx];
    }
    __syncthreads();
    #pragma unroll
    for (int p = 0; p < 4; ++p){
        int r = ty + p*8;
        kT[(size_t)(eb*32 + r)*DIN + kb*32 + tx] = f2bf(tile[tx][r] * 0.1f);
    }
}

// v f32 -> v bf16 (natural [b][j][e]) and vT bf16 ([b][e][j]) + masked-max partials
__global__ void prep_v(const float* __restrict__ v, const float* __restrict__ mask,
                       unsigned short* __restrict__ vbf, unsigned short* __restrict__ vT,
                       float* __restrict__ part){
    __shared__ float tile[32][33];
    __shared__ float pmax_l[8][33];
    int tx = threadIdx.x & 31, ty = threadIdx.x >> 5;
    int jb = blockIdx.x, eb = blockIdx.y, b = blockIdx.z;
    const size_t vbase = (size_t)b*LV*DOUT;
    #pragma unroll
    for (int p = 0; p < 4; ++p){
        int r = ty + p*8;
        size_t idx = vbase + (size_t)(jb*32 + r)*DOUT + eb*32 + tx;
        float val = v[idx];
        tile[r][tx] = val;
        vbf[idx] = f2bf(val);
    }
    __syncthreads();
    const size_t tbase = (size_t)b*DOUT*LV;
    #pragma unroll
    for (int p = 0; p < 4; ++p){
        int r = ty + p*8;
        vT[tbase + (size_t)(eb*32 + r)*LV + jb*32 + tx] = f2bf(tile[tx][r]);
    }
    // masked max over this tile's 32 j for each of 32 e
    float m = -3e38f;
    #pragma unroll
    for (int k2 = 0; k2 < 4; ++k2){
        int j = ty*4 + k2;
        float msk = mask[b*LV + jb*32 + j];
        m = fmaxf(m, tile[j][tx] - (1.0f - msk)*1e10f);
    }
    pmax_l[ty][tx] = m;
    __syncthreads();
    if (ty == 0){
        float mm = pmax_l[0][tx];
        #pragma unroll
        for (int c = 1; c < 8; ++c) mm = fmaxf(mm, pmax_l[c][tx]);
        part[((size_t)b*64 + jb)*DOUT + eb*32 + tx] = mm;
    }
}

__global__ void mv_final(const float* __restrict__ part, float* __restrict__ mv){
    int b = blockIdx.x; int e = threadIdx.x;
    float m = -3e38f;
    #pragma unroll
    for (int c = 0; c < 64; ++c) m = fmaxf(m, part[((size_t)b*64 + c)*DOUT + e]);
    mv[b*DOUT + e] = m;
}

// qw[b*Lq+l][e] = sum_d q[..][d] * kT[e][d]  (bf16 MFMA, f32 acc, bf16 out)
__global__ __launch_bounds__(256) void gemm_qw(const float* __restrict__ q,
                                               const unsigned short* __restrict__ kT,
                                               unsigned short* __restrict__ qw){
    int bid = blockIdx.x;
    int mb = bid >> 1, nb = bid & 1;
    int w = threadIdx.x >> 6, lane = threadIdx.x & 63;
    int li = lane & 15, lg = lane >> 4;
    int i0 = mb*64 + w*16;
    int n0 = nb*256;
    f32x4 acc[16];
    #pragma unroll
    for (int t = 0; t < 16; ++t) acc[t] = (f32x4){0.f,0.f,0.f,0.f};
    for (int ks = 0; ks < 16; ++ks){
        const float* qp = q + (size_t)(i0 + li)*DIN + ks*32 + lg*8;
        float4 lo = *(const float4*)qp;
        float4 hi = *(const float4*)(qp + 4);
        short8v af;
        af[0]=(short)f2bf(lo.x); af[1]=(short)f2bf(lo.y); af[2]=(short)f2bf(lo.z); af[3]=(short)f2bf(lo.w);
        af[4]=(short)f2bf(hi.x); af[5]=(short)f2bf(hi.y); af[6]=(short)f2bf(hi.z); af[7]=(short)f2bf(hi.w);
        #pragma unroll
        for (int t = 0; t < 16; ++t){
            short8v bf = *(const short8v*)(kT + (size_t)(n0 + t*16 + li)*DIN + ks*32 + lg*8);
            acc[t] = __builtin_amdgcn_mfma_f32_16x16x32_bf16(af, bf, acc[t], 0, 0, 0);
        }
    }
    #pragma unroll
    for (int t = 0; t < 16; ++t)
        #pragma unroll
        for (int r = 0; r < 4; ++r)
            qw[(size_t)(i0 + 4*lg + r)*DOUT + n0 + t*16 + li] = f2bf(acc[t][r]);
}

// Flash v7: r3-verified layouts + counted-vmcnt pipeline.
// A-tile [32j][512e] XOR-swizzled (pre-swizzled global source, swizzled read);
// T-tile [512e][32j] linear. Double-buffered; 16 global_load_lds per tile per
// wave; SBAR/stage/VMCNT16/SBAR per iteration (staging never drains to 0).
__global__ __launch_bounds__(256, 1) void flash(const unsigned short* __restrict__ qw,
                                                const unsigned short* __restrict__ vbf,
                                                const unsigned short* __restrict__ vT,
                                                const float* __restrict__ mask,
                                                const float* __restrict__ qf32,
                                                const float* __restrict__ mv,
                                                float* __restrict__ out){
    __shared__ __align__(16) short A_t[2][KT*512];   // 2x32KB, [j][e] swizzled
    __shared__ __align__(16) short T_t[2][512*KT];   // 2x32KB, [e][j] linear
    __shared__ __align__(16) float maskL[2048];      // 8KB mask row
    __shared__ short P_lds[4][16][40];

    const int bid = blockIdx.x;
    const int b = bid & 7, qt = bid >> 3;   // batch -> XCD pin
    const int tid = threadIdx.x;
    const int w = tid >> 6, lane = tid & 63;
    const int li = lane & 15, lg = lane >> 4;
    const int i0 = qt*64 + w*16;

    const unsigned short* vb  = vbf + (size_t)b*LV*DOUT;
    const unsigned short* vTb = vT  + (size_t)b*DOUT*LV;
    const float* mkb = mask + b*LV;

    // q B-fragments (plain loads; compiler inserts its own waits before use)
    short8v qf[16];
    const unsigned short* qrow = qw + (size_t)(b*LQ + i0 + li)*DIN;
    #pragma unroll
    for (int ks = 0; ks < 16; ++ks)
        qf[ks] = *(const short8v*)(qrow + ks*32 + lg*8);

    // r3-verified staging (16 gload16 per wave per tile)
    auto stage = [&](int j0g, int bufsel){
        #pragma unroll
        for (int p = 0; p < 8; ++p){
            int j = w*8 + p;      // local row 0..31
            gload16(vb + (size_t)(j0g + j)*DOUT + ((lane ^ (j&7))*8), &A_t[bufsel][j*512]);
        }
        #pragma unroll
        for (int p = 0; p < 8; ++p){
            int e = w*128 + p*16 + (lane >> 2);
            gload16(vTb + (size_t)e*LV + j0g + (lane&3)*8, &T_t[bufsel][(w*128 + p*16)*KT]);
        }
    };

    f32x4 accO[32];
    #pragma unroll
    for (int t = 0; t < 32; ++t) accO[t] = (f32x4){0.f,0.f,0.f,0.f};
    float mrun = -1e30f, srun = 0.0f;

    // prologue: stage jt0 -> buf0; mask row -> LDS; stage jt1 -> buf1
    stage(0, 0);
    gload16(mkb + tid*4,        (char*)maskL + w*1024);
    gload16(mkb + 1024 + tid*4, (char*)maskL + 4096 + w*1024);
    stage(KT, 1);
    VMCNT16;     // buf0 + mask landed; buf1's 16 still flying
    SBAR;

    const int key = li & 7;
    for (int jt = 0; jt < 64; ++jt){
        const int bs = jt & 1;
        const short* Ac = &A_t[bs][0];
        const short* Tc = &T_t[bs][0];
        const int j0 = jt*KT;

        // mask bias from LDS (broadcast, conflict-free)
        f32x4 mk0 = *(const f32x4*)&maskL[j0 + 4*lg];
        f32x4 mk1 = *(const f32x4*)&maskL[j0 + 16 + 4*lg];

        // S^T from swizzled A-tile: row j0+{li,li+16}, unit (ks*4+lg)^key
        f32x4 s0a = (f32x4){0.f,0.f,0.f,0.f}, s0b = s0a, s1a = s0a, s1b = s0a;
        __builtin_amdgcn_s_setprio(1);
        #pragma unroll
        for (int ks = 0; ks < 8; ++ks){
            short8v a = *(const short8v*)&Ac[li*512 + (((ks*4 + lg)^key)*8)];
            s0a = __builtin_amdgcn_mfma_f32_16x16x32_bf16(a, qf[ks], s0a, 0, 0, 0);
        }
        #pragma unroll
        for (int ks = 8; ks < 16; ++ks){
            short8v a = *(const short8v*)&Ac[li*512 + (((ks*4 + lg)^key)*8)];
            s0b = __builtin_amdgcn_mfma_f32_16x16x32_bf16(a, qf[ks], s0b, 0, 0, 0);
        }
        #pragma unroll
        for (int ks = 0; ks < 8; ++ks){
            short8v a = *(const short8v*)&Ac[(li+16)*512 + (((ks*4 + lg)^key)*8)];
            s1a = __builtin_amdgcn_mfma_f32_16x16x32_bf16(a, qf[ks], s1a, 0, 0, 0);
        }
        #pragma unroll
        for (int ks = 8; ks < 16; ++ks){
            short8v a = *(const short8v*)&Ac[(li+16)*512 + (((ks*4 + lg)^key)*8)];
            s1b = __builtin_amdgcn_mfma_f32_16x16x32_bf16(a, qf[ks], s1b, 0, 0, 0);
        }
        __builtin_amdgcn_s_setprio(0);

        float sv[8];
        #pragma unroll
        for (int r = 0; r < 4; ++r){
            sv[r]     = s0a[r] + s0b[r] + (mk0[r] - 1.0f)*1e10f;
            sv[4 + r] = s1a[r] + s1b[r] + (mk1[r] - 1.0f)*1e10f;
        }
        float pmax = sv[0];
        #pragma unroll
        for (int k = 1; k < 8; ++k) pmax = fmaxf(pmax, sv[k]);
        pmax = fmaxf(pmax, __shfl_xor(pmax, 16));
        pmax = fmaxf(pmax, __shfl_xor(pmax, 32));
        float mnew = fmaxf(mrun, pmax);
        float al = __expf(mrun - mnew);
        float p[8]; float psum = 0.f;
        #pragma unroll
        for (int k = 0; k < 8; ++k){ p[k] = __expf(sv[k] - mnew); psum += p[k]; }
        psum += __shfl_xor(psum, 16);
        psum += __shfl_xor(psum, 32);
        srun = srun*al + psum;
        mrun = mnew;

        if (!__all(al == 1.0f)){  // skip O-rescale when running max unchanged
            float alr[4];
            #pragma unroll
            for (int r = 0; r < 4; ++r) alr[r] = __shfl(al, 4*lg + r);
            #pragma unroll
            for (int t = 0; t < 32; ++t)
                #pragma unroll
                for (int r = 0; r < 4; ++r) accO[t][r] *= alr[r];
        }

        // pack P -> per-wave LDS [i=li][j], read PV A-frag A[i=li][j=lg*8..+7]
        #pragma unroll
        for (int s2 = 0; s2 < 2; ++s2)
            #pragma unroll
            for (int k = 0; k < 2; ++k){
                unsigned lo2 = f2bf(p[s2*4 + 2*k]);
                unsigned hi2 = f2bf(p[s2*4 + 2*k + 1]);
                *(unsigned*)&P_lds[w][li][s2*16 + 4*lg + 2*k] = lo2 | (hi2 << 16);
            }
        short8v pa = *(const short8v*)&P_lds[w][li][lg*8];   // same-wave RAW

        // PV from T-tile: B[k=j][n=e], row e=t*16+li, k-span lg*8..+7
        __builtin_amdgcn_s_setprio(1);
        #pragma unroll
        for (int t = 0; t < 32; ++t){
            short8v vf = *(const short8v*)&Tc[(t*16 + li)*KT + lg*8];
            accO[t] = __builtin_amdgcn_mfma_f32_16x16x32_bf16(pa, vf, accO[t], 0, 0, 0);
        }
        __builtin_amdgcn_s_setprio(0);

        SBAR;                               // all waves consumed buf bs
        if (jt + 2 < 64){ stage((jt+2)*KT, bs); VMCNT16; }  // drains stage(jt+1)
        else if (jt == 62){ VMCNT0; }       // tail: ensure jt63's tile landed
        SBAR;                               // next buffer ready for all waves
    }

    // epilogue: o writeout (per-wave complete softmax state)
    float inv[4];
    #pragma unroll
    for (int r = 0; r < 4; ++r) inv[r] = 1.0f / __shfl(srun, 4*lg + r);
    #pragma unroll
    for (int t = 0; t < 32; ++t)
        #pragma unroll
        for (int r = 0; r < 4; ++r)
            out[(size_t)(b*LQ + i0 + 4*lg + r)*1536 + t*16 + li] = accO[t][r]*inv[r];

    // fused q passthrough + mv broadcast for this block's 64 rows
    {
        const float4* q4  = (const float4*)qf32;
        const float4* mv4 = (const float4*)mv;
        float4* o4 = (float4*)out;
        #pragma unroll 4
        for (int idx = tid; idx < 64*128; idx += 256){
            int row = idx >> 7, c = idx & 127;
            size_t grow = (size_t)b*LQ + qt*64 + row;
            o4[grow*384 + 128 + c] = q4[grow*128 + c];
            o4[grow*384 + 256 + c] = mv4[b*128 + c];
        }
    }
}

extern "C" void kernel_launch(void* const* d_in, const int* in_sizes, int n_in,
                              void* d_out, int out_size, void* d_ws, size_t ws_size,
                              hipStream_t stream){
    const float* q     = (const float*)d_in[0];
    const float* v     = (const float*)d_in[1];
    const float* vmask = (const float*)d_in[2];
    const float* kern  = (const float*)d_in[3];
    float* out = (float*)d_out;
    char* ws = (char*)d_ws;

    const size_t SZ_QW = (size_t)NB*LQ*DOUT*2;       // 16 MB
    unsigned short* qw  = (unsigned short*)(ws);
    unsigned short* vbf = (unsigned short*)(ws + SZ_QW);
    unsigned short* vT  = (unsigned short*)(ws + 2*SZ_QW);
    unsigned short* kT  = (unsigned short*)(ws + 3*SZ_QW);
    float* mv   = (float*)(ws + 3*SZ_QW + 524288);
    float* part = (float*)(ws + 3*SZ_QW + 524288 + 16384);

    hipLaunchKernelGGL(prep_kT,  dim3(16,16),   dim3(256), 0, stream, kern, kT);
    hipLaunchKernelGGL(prep_v,   dim3(64,16,8), dim3(256), 0, stream, v, vmask, vbf, vT, part);
    hipLaunchKernelGGL(mv_final, dim3(8),       dim3(512), 0, stream, part, mv);
    hipLaunchKernelGGL(gemm_qw,  dim3(512),     dim3(256), 0, stream, q, kT, qw);
    hipLaunchKernelGGL(flash,    dim3(256),     dim3(256), 0, stream, qw, vbf, vT, vmask, q, mv, out);
}